// Round 7
// baseline (1517.351 us; speedup 1.0000x reference)
//
#include <hip/hip_runtime.h>

// CustomRNN: B=128, T=64, D=H=256, L=2, 3-node cell.
// Round 12: SYSTOLIC REGISTER/LDS-RESIDENT PIPELINE. r11 confirmed the
// streaming wall: 448 KB/t/CU at ~23.8 B/cyc = 501us, and per-CU ingest
// is CU-internal (r7/r9). Total weights = 67MB; on-chip storage across
// 256 CUs = ~170MB+. So: 192 stage-WGs own their timestep's weights
// PERMANENTLY (node0 matrix in LDS via proven swizzled dma16 preload;
// nodes1,2 as 128 VGPRs of B-fragments). Batch groups g=0..7 flow through:
//   L0(t): h0'(g,t-1) -> cell -> h0'(g,t)     [64 stages, recurrent chain]
//   M3(t): p3 = h0'(g,t)@Win1[t]+b1[0]        [64 leaf stages, off-chain]
//   L1(t): h1'(g,t-1) + p3(g,t) -> h1'(g,t)   [64 stages, recurrent chain]
// DAG strictly forward -> deadlock-free by construction (r6 failed on
// CYCLIC exchange; this has none). Handoffs: r5/r11-proven release/acquire
// (agent scope, magic-tagged); polls bounded (1M iters) so a bug yields
// wrong-answer, not a hung container. Steady-state DMA = ZERO (no vmcnt
// ledger at all). Critical path ~73 hops; T_hop ~1-1.5us -> ~100-160us.

typedef _Float16 f16;
typedef __attribute__((ext_vector_type(8))) _Float16 f16x8;
typedef __attribute__((ext_vector_type(4))) float f32x4;
typedef __attribute__((ext_vector_type(4))) float float4v;

#define Tt 64
#define FLAG_MAGIC 0x52570000

// ---- workspace byte offsets ----
// Wh0T f16 25,165,824 | Win1T f16 8,388,608 | Wh1T f16 25,165,824
// Win0T f16 8,388,608 | xw f32 8,388,608 | h0seq f16 4,194,304
// p3seq f32 8,388,608 | h1seq f16 4,194,304 | flags 6,144  => ~92.3 MB
#define WS_WH0T   0
#define WS_WIN1T  25165824
#define WS_WH1T   33554432
#define WS_WIN0T  58720256
#define WS_XW     67108864
#define WS_H0SEQ  75497472
#define WS_P3SEQ  79691776
#define WS_H1SEQ  88080384
#define WS_FLAGS  92274688

// ---------------- helpers ----------------
__device__ __forceinline__ void sb() { __builtin_amdgcn_sched_barrier(0); }

template <int N>
__device__ __forceinline__ void waitvm() {
  __builtin_amdgcn_s_waitcnt(0x0F70 | (N & 15) | ((N >> 4) << 14));
}
__device__ __forceinline__ void waitlgkm0() { __builtin_amdgcn_s_waitcnt(0xC07F); }

__device__ __forceinline__ void barx() {
  asm volatile("s_waitcnt lgkmcnt(0)\n\ts_barrier" ::: "memory");
}

__device__ __forceinline__ void dma16(const void* g, void* l) {
  __builtin_amdgcn_global_load_lds(
      (const __attribute__((address_space(1))) unsigned int*)g,
      (__attribute__((address_space(3))) unsigned int*)l, 16, 0, 0);
}

__device__ __forceinline__ float tanh_fast(float x) {
  float xc = fminf(fmaxf(x, -15.f), 15.f);
  float e = __expf(2.f * xc);
  return (e - 1.f) / (e + 1.f);
}
__device__ __forceinline__ float sigmoid_fast(float x) { return 1.f / (1.f + __expf(-x)); }

// acquire with bounded spin: a protocol bug becomes a wrong answer
// (visible, with counters), never a hung container.
__device__ __forceinline__ void acquire(const int* f, int want) {
  for (int i = 0; i < (1 << 20); ++i) {
    if (__hip_atomic_load(f, __ATOMIC_ACQUIRE, __HIP_MEMORY_SCOPE_AGENT) == want) return;
  }
}

// ---------------- transpose+convert: [k][n] f32 -> [n][k] f16 ----------------
// 512 matrices: 192 Wh0 + 64 Win1 + 192 Wh1 + 64 Win0
__global__ __launch_bounds__(256) void transpose_cvt_kernel(
    const float* __restrict__ Wh0, const float* __restrict__ Win1,
    const float* __restrict__ Wh1, const float* __restrict__ Win0,
    f16* __restrict__ Wh0T, f16* __restrict__ Win1T, f16* __restrict__ Wh1T,
    f16* __restrict__ Win0T) {
  __shared__ float tile[256 * 33];
  const int bid = blockIdx.x;
  const int mat = bid >> 3, n0 = (bid & 7) << 5;
  const float* src; f16* dst;
  if (mat < 192)      { src = Wh0  + (size_t)mat * 65536;         dst = Wh0T  + (size_t)mat * 65536; }
  else if (mat < 256) { src = Win1 + (size_t)(mat - 192) * 65536; dst = Win1T + (size_t)(mat - 192) * 65536; }
  else if (mat < 448) { src = Wh1  + (size_t)(mat - 256) * 65536; dst = Wh1T  + (size_t)(mat - 256) * 65536; }
  else                { src = Win0 + (size_t)(mat - 448) * 65536; dst = Win0T + (size_t)(mat - 448) * 65536; }
  const int tid = threadIdx.x;
  const int c2 = tid & 15, kl = tid >> 4;
#pragma unroll
  for (int p = 0; p < 16; ++p) {
    const int k = kl + p * 16;
    float2 v = *(const float2*)(src + k * 256 + n0 + c2 * 2);
    tile[k * 33 + c2 * 2]     = v.x;
    tile[k * 33 + c2 * 2 + 1] = v.y;
  }
  __syncthreads();
  const int n = tid >> 5, c = tid & 31;
#pragma unroll
  for (int it = 0; it < 4; ++it) {
    const int nn = n + it * 8;
    f16x8 vv;
#pragma unroll
    for (int i = 0; i < 8; ++i) vv[i] = (f16)tile[(c * 8 + i) * 33 + nn];
    *(f16x8*)((char*)dst + (size_t)(n0 + nn) * 512 + c * 16) = vv;
  }
}

// ---------------- xw precompute: xw[t,b,h] = x[b,t,:]@Win0[t] + b0[t,0,h] ----
__global__ __launch_bounds__(512, 2) void xw_kernel(
    const float* __restrict__ x, const f16* __restrict__ Win0T,
    const float* __restrict__ b0, float* __restrict__ xw) {
  const int t = blockIdx.x >> 3, bb = blockIdx.x & 7;
  const int rb = bb << 4;
  const int tid = threadIdx.x, lane = tid & 63, w = tid >> 6;
  const int q = lane >> 4, mn = lane & 15, dr = q * 4;
  const f16* wt = Win0T + (size_t)t * 65536;
  const float4v* xr = (const float4v*)(x + ((size_t)(rb + mn) * Tt + t) * 256);
  f32x4 acc[2] = {{0.f,0.f,0.f,0.f},{0.f,0.f,0.f,0.f}};
#pragma unroll
  for (int kt = 0; kt < 8; ++kt) {
    const int k0 = kt * 32 + q * 8;
    float4v x0 = xr[k0 / 4], x1 = xr[k0 / 4 + 1];
    f16x8 a = {(f16)x0.x, (f16)x0.y, (f16)x0.z, (f16)x0.w,
               (f16)x1.x, (f16)x1.y, (f16)x1.z, (f16)x1.w};
#pragma unroll
    for (int nt = 0; nt < 2; ++nt) {
      f16x8 b = *(const f16x8*)(wt + (size_t)(w * 32 + nt * 16 + mn) * 256 + k0);
      acc[nt] = __builtin_amdgcn_mfma_f32_16x16x32_f16(a, b, acc[nt], 0, 0, 0);
    }
  }
#pragma unroll
  for (int nt = 0; nt < 2; ++nt) {
    const int n = w * 32 + nt * 16 + mn;
    const float bv = b0[(size_t)t * 768 + n];
#pragma unroll
    for (int r = 0; r < 4; ++r)
      xw[(size_t)t * 32768 + (size_t)(rb + dr + r) * 256 + n] = acc[nt][r] + bv;
  }
}

// ---- matmul: A from regs (af[0..3] lo / af[4..7] hi), B from one LDS half
__device__ __forceinline__ void mmLDS(f32x4 (&acc)[2], const f16x8* af,
                                      const char* lw, const int (&bo)[4]) {
  f16x8 b[8];
#pragma unroll
  for (int kt = 0; kt < 4; ++kt) {
    b[kt * 2]     = *(const f16x8*)(lw + bo[kt]);
    b[kt * 2 + 1] = *(const f16x8*)(lw + bo[kt] + 4096);
  }
  sb();
  waitlgkm0();
  sb();
#pragma unroll
  for (int kt = 0; kt < 4; ++kt) {
    acc[0] = __builtin_amdgcn_mfma_f32_16x16x32_f16(af[kt], b[kt * 2],     acc[0], 0, 0, 0);
    acc[1] = __builtin_amdgcn_mfma_f32_16x16x32_f16(af[kt], b[kt * 2 + 1], acc[1], 0, 0, 0);
  }
}

// ---- matmul: A from nbuf (full K), B from register fragments wr[16]
__device__ __forceinline__ void mmREG(f32x4 (&acc)[2], const char* nrow,
                                      const f16x8 (&wr)[16], int q) {
  f16x8 a[8];
#pragma unroll
  for (int kt = 0; kt < 8; ++kt)
    a[kt] = *(const f16x8*)(nrow + kt * 64 + q * 16);
  sb();
  waitlgkm0();
  sb();
#pragma unroll
  for (int kt = 0; kt < 8; ++kt) {
    acc[0] = __builtin_amdgcn_mfma_f32_16x16x32_f16(a[kt], wr[kt],     acc[0], 0, 0, 0);
    acc[1] = __builtin_amdgcn_mfma_f32_16x16x32_f16(a[kt], wr[8 + kt], acc[1], 0, 0, 0);
  }
}

// ---------------- systolic stage kernel: grid 192 ----------------
// bid 0..63: L0 stage t | 64..127: M3 stage t | 128..191: L1 stage t
__global__ __launch_bounds__(512, 2) void stage_kernel(
    const float* __restrict__ hidden,
    const f16* __restrict__ Wh0T, const float* __restrict__ b0,
    const f16* __restrict__ Win1T, const f16* __restrict__ Wh1T,
    const float* __restrict__ b1, const float* __restrict__ xw,
    f16* __restrict__ h0seq, float* __restrict__ p3seq, f16* __restrict__ h1seq,
    int* __restrict__ flags, float* __restrict__ out) {
  __shared__ __align__(16) char smem[139520];
  char* ldsW = smem;                 // 8 waves x 16KB resident weight slice
  char* nbuf = smem + 131072;        // [16][528] node-value exchange

  const int tid = threadIdx.x, lane = tid & 63, w = tid >> 6;
  const int q = lane >> 4, mn = lane & 15;
  const int dr = q * 4, nc = w * 32 + mn;
  const int wsl = w * 16384;
  char* lwA = ldsW + wsl;            // k-lo half (8KB)
  char* lwB = lwA + 8192;            // k-hi half

  int off[8], bo[4];
#pragma unroll
  for (int d = 0; d < 8; ++d) {
    const int row = 4 * d + q;
    off[d] = row * 512 + ((mn ^ (row & 15)) << 4);
  }
#pragma unroll
  for (int kt = 0; kt < 4; ++kt)
    bo[kt] = mn * 256 + (((kt * 4 + q) ^ mn) << 4);

  const int bid = blockIdx.x;
  const int kind = bid >> 6;         // 0=L0, 1=M3, 2=L1
  const int t = bid & 63;
  const bool lastT = (t == Tt - 1);
  const int tag = FLAG_MAGIC | (t + 1);

  int* fL0 = flags;                  // [g*64+t]
  int* fM3 = flags + 512;
  int* fL1 = flags + 1024;

  const f32x4 zero4 = {0.f, 0.f, 0.f, 0.f};

  if (kind == 0) {
    // ================= L0 stage t =================
    const char* WB = (const char*)Wh0T + (size_t)t * 393216;
    { // preload node0 -> LDS (proven swizzled layout)
#pragma unroll
      for (int d = 0; d < 8; ++d) dma16(WB + wsl + off[d], lwA + d * 1024);
#pragma unroll
      for (int d = 0; d < 8; ++d) dma16(WB + wsl + 256 + off[d], lwB + d * 1024);
    }
    // preload nodes1,2 -> registers (B-fragment layout, one-time strided)
    f16x8 w1r[16], w2r[16];
    {
      const char* B1 = WB + 131072;
      const char* B2 = WB + 262144;
#pragma unroll
      for (int nt = 0; nt < 2; ++nt)
#pragma unroll
        for (int kt = 0; kt < 8; ++kt) {
          const size_t o = (size_t)(nc + nt * 16) * 512 + kt * 64 + q * 16;
          w1r[nt * 8 + kt] = *(const f16x8*)(B1 + o);
          w2r[nt * 8 + kt] = *(const f16x8*)(B2 + o);
        }
    }
    const float bv1a = b0[(size_t)t * 768 + 256 + nc], bv1b = b0[(size_t)t * 768 + 256 + nc + 16];
    const float bv2a = b0[(size_t)t * 768 + 512 + nc], bv2b = b0[(size_t)t * 768 + 512 + nc + 16];
    waitvm<0>();
    barx();

#pragma unroll 1
    for (int g = 0; g < 8; ++g) {
      const int rb = g << 4;
      if (t > 0) acquire(&fL0[g * 64 + t - 1], FLAG_MAGIC | t);
      sb();
      // A-fragments of h0'(g,t-1) (t=0: initial hidden, f32 cvt)
      f16x8 af[8];
      if (t > 0) {
        const char* ht = (const char*)h0seq + (size_t)(g * 64 + t - 1) * 8192;
#pragma unroll
        for (int kt = 0; kt < 8; ++kt)
          af[kt] = *(const f16x8*)(ht + mn * 512 + kt * 64 + q * 16);
      } else {
        const float* hp = hidden + (size_t)rb * 256;
#pragma unroll
        for (int kt = 0; kt < 8; ++kt) {
          const float4v* p = (const float4v*)(hp + mn * 256 + kt * 32 + q * 8);
          float4v x0 = p[0], x1 = p[1];
          f16x8 v;
          v[0] = (f16)x0.x; v[1] = (f16)x0.y; v[2] = (f16)x0.z; v[3] = (f16)x0.w;
          v[4] = (f16)x1.x; v[5] = (f16)x1.y; v[6] = (f16)x1.z; v[7] = (f16)x1.w;
          af[kt] = v;
        }
      }
      float xwv[2][4];
#pragma unroll
      for (int nt = 0; nt < 2; ++nt)
#pragma unroll
        for (int r = 0; r < 4; ++r)
          xwv[nt][r] = xw[(size_t)t * 32768 + (size_t)(rb + dr + r) * 256 + nc + nt * 16];
      sb();

      // m0: n0 = tanh(h_prev @ Wh0[0] + xw)
      f32x4 acc[2];
      acc[0] = zero4; acc[1] = zero4;
      mmLDS(acc, af,     lwA, bo);
      mmLDS(acc, af + 4, lwB, bo);
      float n0v[2][4], n1v[2][4];
#pragma unroll
      for (int nt = 0; nt < 2; ++nt)
#pragma unroll
        for (int r = 0; r < 4; ++r) {
          float v = tanh_fast(acc[nt][r] + xwv[nt][r]);
          n0v[nt][r] = v;
          *(f16*)(nbuf + (dr + r) * 528 + (nc + nt * 16) * 2) = (f16)v;
        }
      barx();  // n0 visible

      // m1: n1 = relu(n0@Wh0[1] + b0[1]) + n0   (B from regs)
      acc[0] = zero4; acc[1] = zero4;
      mmREG(acc, nbuf + mn * 528, w1r, q);
#pragma unroll
      for (int nt = 0; nt < 2; ++nt) {
        const float bv = nt ? bv1b : bv1a;
#pragma unroll
        for (int r = 0; r < 4; ++r)
          n1v[nt][r] = fmaxf(acc[nt][r] + bv, 0.f) + n0v[nt][r];
      }
      barx();  // WAR: n0 reads done
#pragma unroll
      for (int nt = 0; nt < 2; ++nt)
#pragma unroll
        for (int r = 0; r < 4; ++r)
          *(f16*)(nbuf + (dr + r) * 528 + (nc + nt * 16) * 2) = (f16)n1v[nt][r];
      barx();  // n1 visible

      // m2: n2 = sigmoid(n1@Wh0[2] + b0[2]) + n0 ; h0' = 0.5(n1+n2)
      acc[0] = zero4; acc[1] = zero4;
      mmREG(acc, nbuf + mn * 528, w2r, q);
      char* hs = (char*)h0seq + (size_t)(g * 64 + t) * 8192;
#pragma unroll
      for (int nt = 0; nt < 2; ++nt) {
        const float bv = nt ? bv2b : bv2a;
#pragma unroll
        for (int r = 0; r < 4; ++r) {
          float s = sigmoid_fast(acc[nt][r] + bv);
          float hv = 0.5f * (n1v[nt][r] + s + n0v[nt][r]);
          *(f16*)(hs + (dr + r) * 512 + (nc + nt * 16) * 2) = (f16)hv;
          if (lastT) out[2097152 + (size_t)(rb + dr + r) * 256 + nc + nt * 16] = hv;
        }
      }
      sb();
      waitvm<0>();           // retire the 8-16 stores (nothing else in flight)
      __syncthreads();
      if (tid == 0)
        __hip_atomic_store(&fL0[g * 64 + t], tag, __ATOMIC_RELEASE, __HIP_MEMORY_SCOPE_AGENT);
      sb();
    }
  } else if (kind == 1) {
    // ================= M3 leaf stage t: p3 = h0'(t)@Win1[t] + b1[0] =========
    const char* WB = (const char*)Win1T + (size_t)t * 131072;
    {
#pragma unroll
      for (int d = 0; d < 8; ++d) dma16(WB + wsl + off[d], lwA + d * 1024);
#pragma unroll
      for (int d = 0; d < 8; ++d) dma16(WB + wsl + 256 + off[d], lwB + d * 1024);
    }
    const float p3ba = b1[(size_t)t * 768 + nc], p3bb = b1[(size_t)t * 768 + nc + 16];
    waitvm<0>();
    barx();

#pragma unroll 1
    for (int g = 0; g < 8; ++g) {
      acquire(&fL0[g * 64 + t], tag);
      sb();
      f16x8 af[8];
      const char* ht = (const char*)h0seq + (size_t)(g * 64 + t) * 8192;
#pragma unroll
      for (int kt = 0; kt < 8; ++kt)
        af[kt] = *(const f16x8*)(ht + mn * 512 + kt * 64 + q * 16);
      sb();
      f32x4 acc[2];
      acc[0] = zero4; acc[1] = zero4;
      mmLDS(acc, af,     lwA, bo);
      mmLDS(acc, af + 4, lwB, bo);
      float* ps = p3seq + (size_t)(g * 64 + t) * 4096;
#pragma unroll
      for (int nt = 0; nt < 2; ++nt) {
        const float bv = nt ? p3bb : p3ba;
#pragma unroll
        for (int r = 0; r < 4; ++r)
          ps[(dr + r) * 256 + nc + nt * 16] = acc[nt][r] + bv;
      }
      sb();
      waitvm<0>();
      __syncthreads();
      if (tid == 0)
        __hip_atomic_store(&fM3[g * 64 + t], tag, __ATOMIC_RELEASE, __HIP_MEMORY_SCOPE_AGENT);
      sb();
    }
  } else {
    // ================= L1 stage t =================
    const char* WB = (const char*)Wh1T + (size_t)t * 393216;
    {
#pragma unroll
      for (int d = 0; d < 8; ++d) dma16(WB + wsl + off[d], lwA + d * 1024);
#pragma unroll
      for (int d = 0; d < 8; ++d) dma16(WB + wsl + 256 + off[d], lwB + d * 1024);
    }
    f16x8 w1r[16], w2r[16];
    {
      const char* B1 = WB + 131072;
      const char* B2 = WB + 262144;
#pragma unroll
      for (int nt = 0; nt < 2; ++nt)
#pragma unroll
        for (int kt = 0; kt < 8; ++kt) {
          const size_t o = (size_t)(nc + nt * 16) * 512 + kt * 64 + q * 16;
          w1r[nt * 8 + kt] = *(const f16x8*)(B1 + o);
          w2r[nt * 8 + kt] = *(const f16x8*)(B2 + o);
        }
    }
    const float bv1a = b1[(size_t)t * 768 + 256 + nc], bv1b = b1[(size_t)t * 768 + 256 + nc + 16];
    const float bv2a = b1[(size_t)t * 768 + 512 + nc], bv2b = b1[(size_t)t * 768 + 512 + nc + 16];
    waitvm<0>();
    barx();

#pragma unroll 1
    for (int g = 0; g < 8; ++g) {
      const int rb = g << 4;
      if (t > 0) acquire(&fL1[g * 64 + t - 1], FLAG_MAGIC | t);
      sb();
      f16x8 af[8];
      if (t > 0) {
        const char* ht = (const char*)h1seq + (size_t)(g * 64 + t - 1) * 8192;
#pragma unroll
        for (int kt = 0; kt < 8; ++kt)
          af[kt] = *(const f16x8*)(ht + mn * 512 + kt * 64 + q * 16);
      } else {
        const float* hp = hidden + 32768 + (size_t)rb * 256;
#pragma unroll
        for (int kt = 0; kt < 8; ++kt) {
          const float4v* p = (const float4v*)(hp + mn * 256 + kt * 32 + q * 8);
          float4v x0 = p[0], x1 = p[1];
          f16x8 v;
          v[0] = (f16)x0.x; v[1] = (f16)x0.y; v[2] = (f16)x0.z; v[3] = (f16)x0.w;
          v[4] = (f16)x1.x; v[5] = (f16)x1.y; v[6] = (f16)x1.z; v[7] = (f16)x1.w;
          af[kt] = v;
        }
      }
      acquire(&fM3[g * 64 + t], tag);
      sb();
      float p3v[2][4];
      const float* ps = p3seq + (size_t)(g * 64 + t) * 4096;
#pragma unroll
      for (int nt = 0; nt < 2; ++nt)
#pragma unroll
        for (int r = 0; r < 4; ++r)
          p3v[nt][r] = ps[(dr + r) * 256 + nc + nt * 16];
      sb();

      // m4: h1_prev @ Wh1[0] ; n0' = tanh(m4 + p3)
      f32x4 acc[2];
      acc[0] = zero4; acc[1] = zero4;
      mmLDS(acc, af,     lwA, bo);
      mmLDS(acc, af + 4, lwB, bo);
      float n0v[2][4], n1v[2][4];
#pragma unroll
      for (int nt = 0; nt < 2; ++nt)
#pragma unroll
        for (int r = 0; r < 4; ++r) {
          float v = tanh_fast(acc[nt][r] + p3v[nt][r]);
          n0v[nt][r] = v;
          *(f16*)(nbuf + (dr + r) * 528 + (nc + nt * 16) * 2) = (f16)v;
        }
      barx();  // n0' visible

      // m5: n1' = relu(n0'@Wh1[1] + b1[1]) + n0'
      acc[0] = zero4; acc[1] = zero4;
      mmREG(acc, nbuf + mn * 528, w1r, q);
#pragma unroll
      for (int nt = 0; nt < 2; ++nt) {
        const float bv = nt ? bv1b : bv1a;
#pragma unroll
        for (int r = 0; r < 4; ++r)
          n1v[nt][r] = fmaxf(acc[nt][r] + bv, 0.f) + n0v[nt][r];
      }
      barx();  // WAR
#pragma unroll
      for (int nt = 0; nt < 2; ++nt)
#pragma unroll
        for (int r = 0; r < 4; ++r)
          *(f16*)(nbuf + (dr + r) * 528 + (nc + nt * 16) * 2) = (f16)n1v[nt][r];
      barx();  // n1' visible

      // m6: n2' = sigmoid(n1'@Wh1[2] + b1[2]) + n0' ; h1' = 0.5(n1'+n2')
      acc[0] = zero4; acc[1] = zero4;
      mmREG(acc, nbuf + mn * 528, w2r, q);
      char* hs = (char*)h1seq + (size_t)(g * 64 + t) * 8192;
#pragma unroll
      for (int nt = 0; nt < 2; ++nt) {
        const float bv = nt ? bv2b : bv2a;
#pragma unroll
        for (int r = 0; r < 4; ++r) {
          float s = sigmoid_fast(acc[nt][r] + bv);
          float hv = 0.5f * (n1v[nt][r] + s + n0v[nt][r]);
          *(f16*)(hs + (dr + r) * 512 + (nc + nt * 16) * 2) = (f16)hv;
          out[((size_t)(rb + dr + r) * Tt + t) * 256 + nc + nt * 16] = hv;
          if (lastT) out[2097152 + 32768 + (size_t)(rb + dr + r) * 256 + nc + nt * 16] = hv;
        }
      }
      sb();
      waitvm<0>();
      __syncthreads();
      if (tid == 0)
        __hip_atomic_store(&fL1[g * 64 + t], tag, __ATOMIC_RELEASE, __HIP_MEMORY_SCOPE_AGENT);
      sb();
    }
  }
}

// ---------------- launch ----------------
extern "C" void kernel_launch(void* const* d_in, const int* in_sizes, int n_in,
                              void* d_out, int out_size, void* d_ws, size_t ws_size,
                              hipStream_t stream) {
  (void)in_sizes; (void)n_in; (void)out_size; (void)ws_size;
  const float* x      = (const float*)d_in[0];
  const float* hidden = (const float*)d_in[1];
  const float* Win0   = (const float*)d_in[2];
  const float* Wh0    = (const float*)d_in[3];
  const float* b0     = (const float*)d_in[4];
  const float* Win1   = (const float*)d_in[5];
  const float* Wh1    = (const float*)d_in[6];
  const float* b1     = (const float*)d_in[7];
  float* out = (float*)d_out;

  char* ws = (char*)d_ws;
  f16* Wh0T   = (f16*)(ws + WS_WH0T);
  f16* Win1T  = (f16*)(ws + WS_WIN1T);
  f16* Wh1T   = (f16*)(ws + WS_WH1T);
  f16* Win0T  = (f16*)(ws + WS_WIN0T);
  float* xwp  = (float*)(ws + WS_XW);
  f16* h0seq  = (f16*)(ws + WS_H0SEQ);
  float* p3p  = (float*)(ws + WS_P3SEQ);
  f16* h1seq  = (f16*)(ws + WS_H1SEQ);
  int* flags  = (int*)(ws + WS_FLAGS);

  transpose_cvt_kernel<<<dim3(4096), dim3(256), 0, stream>>>(
      Wh0, Win1, Wh1, Win0, Wh0T, Win1T, Wh1T, Win0T);
  xw_kernel<<<dim3(512), dim3(512), 0, stream>>>(x, Win0T, b0, xwp);
  stage_kernel<<<dim3(192), dim3(512), 0, stream>>>(
      hidden, Wh0T, b0, Win1T, Wh1T, b1, xwp, h0seq, p3p, h1seq, flags, out);
}